// Round 2
// baseline (124.906 us; speedup 1.0000x reference)
//
#include <hip/hip_runtime.h>

#define B_DIM 4096
#define T_DIM 16384
#define WAVES_PER_BLOCK 4
#define PER_LANE 8
#define CHUNK (64 * PER_LANE)   // 512 samples per wave per iteration

typedef float f32x4 __attribute__((ext_vector_type(4)));

struct M2 { float a, b, c, d; };  // [[a,b],[c,d]]

__device__ inline M2 m2mul(const M2& X, const M2& Y) {
    M2 r;
    r.a = fmaf(X.a, Y.a, X.b * Y.c);
    r.b = fmaf(X.a, Y.b, X.b * Y.d);
    r.c = fmaf(X.c, Y.a, X.d * Y.c);
    r.d = fmaf(X.c, Y.b, X.d * Y.d);
    return r;
}

__global__ __launch_bounds__(256, 4) void biquad_scan_kernel(
    const float* __restrict__ x, const float* __restrict__ v0in,
    const float* __restrict__ pb0, const float* __restrict__ pb1,
    const float* __restrict__ pb2, const float* __restrict__ pa1,
    const float* __restrict__ pa2,
    float* __restrict__ y, float* __restrict__ vout)
{
    const int lane = threadIdx.x & 63;
    const int wave = threadIdx.x >> 6;
    const int row  = blockIdx.x * WAVES_PER_BLOCK + wave;
    if (row >= B_DIM) return;

    const float b0 = *pb0, b1 = *pb1, b2 = *pb2, a1 = *pa1, a2 = *pa2;
    const float na1 = -a1, na2 = -a2;
    const float c0 = b1 - a1 * b0;   // state-update input coeffs
    const float c1 = b2 - a2 * b0;

    // A = [[-a1, 1], [-a2, 0]]
    M2 A  { na1, 1.0f, na2, 0.0f };
    M2 A2 = m2mul(A, A);
    M2 A3 = m2mul(A2, A);
    M2 A4 = m2mul(A2, A2);
    M2 A5 = m2mul(A4, A);
    M2 A6 = m2mul(A4, A2);
    M2 A7 = m2mul(A4, A3);
    M2 A8 = m2mul(A4, A4);

    // Row-0 of A^k for the y-correction (y_k = yz_k + (A^k)[0,:]·v_begin)
    const float p1a = A .a, p1b = A .b;
    const float p2a = A2.a, p2b = A2.b;
    const float p3a = A3.a, p3b = A3.b;
    const float p4a = A4.a, p4b = A4.b;
    const float p5a = A5.a, p5b = A5.b;
    const float p6a = A6.a, p6b = A6.b;
    const float p7a = A7.a, p7b = A7.b;

    // S[s] = A^(8*2^s) scan matrices; Q = A^(8*lane); R = A^512.
    M2 S0, S1, S2, S3, S4, S5;
    M2 Q { 1.f, 0.f, 0.f, 1.f };
    M2 M = A8;
    S0 = M; if (lane & 1)  Q = m2mul(M, Q); M = m2mul(M, M);
    S1 = M; if (lane & 2)  Q = m2mul(M, Q); M = m2mul(M, M);
    S2 = M; if (lane & 4)  Q = m2mul(M, Q); M = m2mul(M, M);
    S3 = M; if (lane & 8)  Q = m2mul(M, Q); M = m2mul(M, M);
    S4 = M; if (lane & 16) Q = m2mul(M, Q); M = m2mul(M, M);
    S5 = M; if (lane & 32) Q = m2mul(M, Q); M = m2mul(M, M);
    const M2 R = M;  // A^512

    const float* xr = x + (size_t)row * T_DIM;
    float*       yr = y + (size_t)row * T_DIM;

    float vc0 = v0in[row * 2 + 0];
    float vc1 = v0in[row * 2 + 1];

    const int NIT = T_DIM / CHUNK;  // 32
    const int STEP4 = CHUNK / 4;    // 128 f32x4 per chunk

    const f32x4* xp = (const f32x4*)xr + lane * 2;
    f32x4*       yp = (f32x4*)yr + lane * 2;

    // depth-2 prefetch: current chunk (ca,cb), next chunk (nb pair)
    f32x4 ca = __builtin_nontemporal_load(&xp[0]);
    f32x4 cb = __builtin_nontemporal_load(&xp[1]);
    xp += STEP4;
    f32x4 pa = __builtin_nontemporal_load(&xp[0]);
    f32x4 pb = __builtin_nontemporal_load(&xp[1]);

    for (int i = 0; i < NIT; ++i) {
        f32x4 ma = {0.f, 0.f, 0.f, 0.f}, mb = {0.f, 0.f, 0.f, 0.f};
        if (i + 2 < NIT) {
            ma = __builtin_nontemporal_load(&xp[STEP4]);
            mb = __builtin_nontemporal_load(&xp[STEP4 + 1]);
        }

        // ---- zero-start fold over 8 samples; record yz_k = b0*x_k + d0 ----
        float d0 = 0.f, d1 = 0.f;
        float yz0, yz1, yz2, yz3, yz4, yz5, yz6, yz7;
        #define FOLD(xs, yz)                                           \
        {   yz = fmaf((xs), b0, d0);                                   \
            float t0 = fmaf(c0, (xs), fmaf(na1, d0, d1));              \
            float t1 = fmaf(na2, d0, c1 * (xs));                       \
            d0 = t0; d1 = t1; }
        FOLD(ca[0], yz0) FOLD(ca[1], yz1) FOLD(ca[2], yz2) FOLD(ca[3], yz3)
        FOLD(cb[0], yz4) FOLD(cb[1], yz5) FOLD(cb[2], yz6) FOLD(cb[3], yz7)
        #undef FOLD

        // ---- inclusive Hillis-Steele scan across lanes ----
        #define SCAN_STEP(Sm, o)                                        \
        {   float q0 = __shfl_up(d0, (unsigned)(o));                    \
            float q1 = __shfl_up(d1, (unsigned)(o));                    \
            if (lane < (o)) { q0 = 0.f; q1 = 0.f; }                     \
            float t0 = fmaf(Sm.a, q0, fmaf(Sm.b, q1, d0));              \
            float t1 = fmaf(Sm.c, q0, fmaf(Sm.d, q1, d1));              \
            d0 = t0; d1 = t1; }
        SCAN_STEP(S0, 1)
        SCAN_STEP(S1, 2)
        SCAN_STEP(S2, 4)
        SCAN_STEP(S3, 8)
        SCAN_STEP(S4, 16)
        SCAN_STEP(S5, 32)
        #undef SCAN_STEP

        // ---- exclusive shift ----
        float e0 = __shfl_up(d0, 1u);
        float e1 = __shfl_up(d1, 1u);
        if (lane == 0) { e0 = 0.f; e1 = 0.f; }

        // ---- per-lane segment start state ----
        const float vb0 = fmaf(Q.a, vc0, fmaf(Q.b, vc1, e0));
        const float vb1 = fmaf(Q.c, vc0, fmaf(Q.d, vc1, e1));

        // ---- y = yz + (A^k)row0 · v_begin (independent 2-FMA per sample) ----
        f32x4 yo0, yo1;
        yo0[0] = yz0 + vb0;
        yo0[1] = fmaf(p1a, vb0, fmaf(p1b, vb1, yz1));
        yo0[2] = fmaf(p2a, vb0, fmaf(p2b, vb1, yz2));
        yo0[3] = fmaf(p3a, vb0, fmaf(p3b, vb1, yz3));
        yo1[0] = fmaf(p4a, vb0, fmaf(p4b, vb1, yz4));
        yo1[1] = fmaf(p5a, vb0, fmaf(p5b, vb1, yz5));
        yo1[2] = fmaf(p6a, vb0, fmaf(p6b, vb1, yz6));
        yo1[3] = fmaf(p7a, vb0, fmaf(p7b, vb1, yz7));

        __builtin_nontemporal_store(yo0, &yp[0]);
        __builtin_nontemporal_store(yo1, &yp[1]);

        // ---- carry: v_carry = A^512 * v_carry + d_inclusive[63] ----
        float t0 = __shfl(d0, 63);
        float t1 = __shfl(d1, 63);
        float nv0 = fmaf(R.a, vc0, fmaf(R.b, vc1, t0));
        float nv1 = fmaf(R.c, vc0, fmaf(R.d, vc1, t1));
        vc0 = nv0; vc1 = nv1;

        ca = pa; cb = pb; pa = ma; pb = mb;
        xp += STEP4;
        yp += STEP4;
    }

    if (lane == 0) {
        vout[row * 2 + 0] = vc0;
        vout[row * 2 + 1] = vc1;
    }
}

extern "C" void kernel_launch(void* const* d_in, const int* in_sizes, int n_in,
                              void* d_out, int out_size, void* d_ws, size_t ws_size,
                              hipStream_t stream) {
    const float* x   = (const float*)d_in[0];
    const float* v0  = (const float*)d_in[1];
    const float* b0  = (const float*)d_in[2];
    const float* b1  = (const float*)d_in[3];
    const float* b2  = (const float*)d_in[4];
    const float* a1  = (const float*)d_in[5];
    const float* a2  = (const float*)d_in[6];

    float* y    = (float*)d_out;
    float* vout = (float*)d_out + (size_t)B_DIM * T_DIM;

    dim3 grid(B_DIM / WAVES_PER_BLOCK);
    dim3 block(64 * WAVES_PER_BLOCK);
    biquad_scan_kernel<<<grid, block, 0, stream>>>(x, v0, b0, b1, b2, a1, a2, y, vout);
}

// Round 3
// 119.144 us; speedup vs baseline: 1.0484x; 1.0484x over previous
//
#include <hip/hip_runtime.h>

#define B_DIM 4096
#define T_DIM 16384
#define WAVES_PER_BLOCK 4
#define CHUNK 256              // samples per wave per iteration (64 lanes * 4)
#define NIT (T_DIM / CHUNK)    // 64

typedef float f32x4 __attribute__((ext_vector_type(4)));

struct M2 { float a, b, c, d; };  // [[a,b],[c,d]]

__device__ inline M2 m2mul(const M2& X, const M2& Y) {
    M2 r;
    r.a = fmaf(X.a, Y.a, X.b * Y.c);
    r.b = fmaf(X.a, Y.b, X.b * Y.d);
    r.c = fmaf(X.c, Y.a, X.d * Y.c);
    r.d = fmaf(X.c, Y.b, X.d * Y.d);
    return r;
}

__global__ __launch_bounds__(256) void biquad_scan_kernel(
    const float* __restrict__ x, const float* __restrict__ v0in,
    const float* __restrict__ pb0, const float* __restrict__ pb1,
    const float* __restrict__ pb2, const float* __restrict__ pa1,
    const float* __restrict__ pa2,
    float* __restrict__ y, float* __restrict__ vout)
{
    const int lane = threadIdx.x & 63;
    const int wave = threadIdx.x >> 6;
    const int row  = blockIdx.x * WAVES_PER_BLOCK + wave;
    if (row >= B_DIM) return;

    const float b0 = *pb0, b1 = *pb1, b2 = *pb2, a1 = *pa1, a2 = *pa2;
    const float na1 = -a1, na2 = -a2;
    const float c0 = b1 - a1 * b0;   // state-update input coeffs
    const float c1 = b2 - a2 * b0;

    // A = [[-a1, 1], [-a2, 0]]
    M2 A  { na1, 1.0f, na2, 0.0f };
    M2 A2 = m2mul(A, A);
    M2 A3 = m2mul(A2, A);
    M2 A4 = m2mul(A2, A2);

    // Row-0 of A^k for the y-correction: y_k = yz_k + (A^k)[0,:]·v_begin
    const float p1a = A .a, p1b = A .b;
    const float p2a = A2.a, p2b = A2.b;
    const float p3a = A3.a, p3b = A3.b;

    // S[s] = A^(4*2^s) scan matrices; Q = A^(4*lane); R = A^256.
    M2 S0, S1, S2, S3, S4, S5;
    M2 Q { 1.f, 0.f, 0.f, 1.f };
    M2 M = A4;
    S0 = M; if (lane & 1)  Q = m2mul(M, Q); M = m2mul(M, M);
    S1 = M; if (lane & 2)  Q = m2mul(M, Q); M = m2mul(M, M);
    S2 = M; if (lane & 4)  Q = m2mul(M, Q); M = m2mul(M, M);
    S3 = M; if (lane & 8)  Q = m2mul(M, Q); M = m2mul(M, M);
    S4 = M; if (lane & 16) Q = m2mul(M, Q); M = m2mul(M, M);
    S5 = M; if (lane & 32) Q = m2mul(M, Q); M = m2mul(M, M);
    const M2 R = M;  // A^256

    const float* xr = x + (size_t)row * T_DIM;
    float*       yr = y + (size_t)row * T_DIM;

    float vc0 = v0in[row * 2 + 0];
    float vc1 = v0in[row * 2 + 1];

    const int S4STEP = CHUNK / 4;   // 64 f32x4 per chunk
    const f32x4* xp = (const f32x4*)xr + lane;
    f32x4*       yp = (f32x4*)yr + lane;

    // depth-4 rolling prefetch: r0..r3 hold chunks i..i+3
    f32x4 r0 = xp[0 * S4STEP];
    f32x4 r1 = xp[1 * S4STEP];
    f32x4 r2 = xp[2 * S4STEP];
    f32x4 r3 = xp[3 * S4STEP];

    #pragma unroll 4
    for (int i = 0; i < NIT; ++i) {
        const f32x4 xv = r0;
        // rotate + issue next prefetch (clamped; tail re-reads last chunk, L2-hot)
        r0 = r1; r1 = r2; r2 = r3;
        int nf = i + 4; if (nf > NIT - 1) nf = NIT - 1;
        r3 = xp[(size_t)nf * S4STEP];

        // ---- zero-start fold over 4 samples; record yz_k = b0*x_k + d0 ----
        float d0 = 0.f, d1 = 0.f;
        float yz0, yz1, yz2, yz3;
        #define FOLD(xs, yz)                                           \
        {   yz = fmaf((xs), b0, d0);                                   \
            float t0 = fmaf(c0, (xs), fmaf(na1, d0, d1));              \
            float t1 = fmaf(na2, d0, c1 * (xs));                       \
            d0 = t0; d1 = t1; }
        FOLD(xv[0], yz0) FOLD(xv[1], yz1) FOLD(xv[2], yz2) FOLD(xv[3], yz3)
        #undef FOLD

        // ---- inclusive Hillis-Steele scan across lanes ----
        #define SCAN_STEP(Sm, o)                                        \
        {   float q0 = __shfl_up(d0, (unsigned)(o));                    \
            float q1 = __shfl_up(d1, (unsigned)(o));                    \
            if (lane < (o)) { q0 = 0.f; q1 = 0.f; }                     \
            float t0 = fmaf(Sm.a, q0, fmaf(Sm.b, q1, d0));              \
            float t1 = fmaf(Sm.c, q0, fmaf(Sm.d, q1, d1));              \
            d0 = t0; d1 = t1; }
        SCAN_STEP(S0, 1)
        SCAN_STEP(S1, 2)
        SCAN_STEP(S2, 4)
        SCAN_STEP(S3, 8)
        SCAN_STEP(S4, 16)
        SCAN_STEP(S5, 32)
        #undef SCAN_STEP

        // ---- exclusive shift ----
        float e0 = __shfl_up(d0, 1u);
        float e1 = __shfl_up(d1, 1u);
        if (lane == 0) { e0 = 0.f; e1 = 0.f; }

        // ---- per-lane segment start state ----
        const float vb0 = fmaf(Q.a, vc0, fmaf(Q.b, vc1, e0));
        const float vb1 = fmaf(Q.c, vc0, fmaf(Q.d, vc1, e1));

        // ---- y = yz + (A^k)row0 · v_begin (independent 2 FMA per sample) ----
        f32x4 yo;
        yo[0] = yz0 + vb0;
        yo[1] = fmaf(p1a, vb0, fmaf(p1b, vb1, yz1));
        yo[2] = fmaf(p2a, vb0, fmaf(p2b, vb1, yz2));
        yo[3] = fmaf(p3a, vb0, fmaf(p3b, vb1, yz3));

        yp[(size_t)i * S4STEP] = yo;

        // ---- carry: v_carry = A^256 * v_carry + d_inclusive[63] ----
        float t0 = __shfl(d0, 63);
        float t1 = __shfl(d1, 63);
        float nv0 = fmaf(R.a, vc0, fmaf(R.b, vc1, t0));
        float nv1 = fmaf(R.c, vc0, fmaf(R.d, vc1, t1));
        vc0 = nv0; vc1 = nv1;
    }

    if (lane == 0) {
        vout[row * 2 + 0] = vc0;
        vout[row * 2 + 1] = vc1;
    }
}

extern "C" void kernel_launch(void* const* d_in, const int* in_sizes, int n_in,
                              void* d_out, int out_size, void* d_ws, size_t ws_size,
                              hipStream_t stream) {
    const float* x   = (const float*)d_in[0];
    const float* v0  = (const float*)d_in[1];
    const float* b0  = (const float*)d_in[2];
    const float* b1  = (const float*)d_in[3];
    const float* b2  = (const float*)d_in[4];
    const float* a1  = (const float*)d_in[5];
    const float* a2  = (const float*)d_in[6];

    float* y    = (float*)d_out;
    float* vout = (float*)d_out + (size_t)B_DIM * T_DIM;

    dim3 grid(B_DIM / WAVES_PER_BLOCK);
    dim3 block(64 * WAVES_PER_BLOCK);
    biquad_scan_kernel<<<grid, block, 0, stream>>>(x, v0, b0, b1, b2, a1, a2, y, vout);
}